// Round 1
// baseline (724.340 us; speedup 1.0000x reference)
//
#include <hip/hip_runtime.h>

// ---------------------------------------------------------------------------
// DistanceLoss pipeline on MI355X (gfx950)
// Stages:
//  0. convert clsW_w fp32 -> bf16                  (conv_w)
//  1. tuple-gather queries+supports -> A bf16      (build_a)
//  2. E = relu(A @ W^T + b)  [4608 x 2048] bf16    (gemm_bt epi=0)
//  3. sq[i] = |E[i]|^2                             (norm_rows)
//  4. D[i][j] = dist(E[i], E[3375+j]) [4608 x1152] (gemm_bt epi=1)
//  5. per-(c,i): rowmax/argmax/group-max stats     (stats_kernel)
//  6. dist_max reduce -> out[0:375]                (dmax_kernel)
//  7. record/mask per (c, other-class)             (record_kernel)
//  8. masked-mean contrast -> out[375:750]         (contrast_kernel)
// ---------------------------------------------------------------------------

typedef __bf16 bf16x8 __attribute__((ext_vector_type(8)));
typedef float f32x4 __attribute__((ext_vector_type(4)));

#define NQT   3375      // 75*45 query-tuple rows
#define MROWS 4500      // 3375 query rows + 1125 support rows
#define MPAD  4608      // 36 * 128
#define K1    4096
#define N1    2048
#define K2    2048
#define LDD   1152      // padded 1125 -> 9*128
#define LDS_S 40        // LDS row stride in bf16 (32 + 8 pad)

__constant__ int P0[45] = {0,0,0,0,0,0,0,0,0,
                           1,1,1,1,1,1,1,1,
                           2,2,2,2,2,2,2,
                           3,3,3,3,3,3,
                           4,4,4,4,4,
                           5,5,5,5,
                           6,6,6,
                           7,7,
                           8};
__constant__ int P1[45] = {1,2,3,4,5,6,7,8,9,
                           2,3,4,5,6,7,8,9,
                           3,4,5,6,7,8,9,
                           4,5,6,7,8,9,
                           5,6,7,8,9,
                           6,7,8,9,
                           7,8,9,
                           8,9,
                           9};

__device__ inline unsigned short f2b(float x) {
  __bf16 b = (__bf16)x;               // RNE
  return __builtin_bit_cast(unsigned short, b);
}
__device__ inline float b2f(unsigned int u16) {
  return __uint_as_float(u16 << 16);
}

// ---- 0: W fp32 -> bf16 -----------------------------------------------------
__global__ void conv_w(const float* __restrict__ W, unsigned short* __restrict__ Wb) {
  int i = blockIdx.x * 256 + threadIdx.x;           // one float4 per thread
  if (i >= (2048 * 4096) / 4) return;
  float4 v = reinterpret_cast<const float4*>(W)[i];
  ushort4 o;
  o.x = f2b(v.x); o.y = f2b(v.y); o.z = f2b(v.z); o.w = f2b(v.w);
  reinterpret_cast<ushort4*>(Wb)[i] = o;
}

// ---- 1: tuple gather -> A [MROWS x 4096] bf16 ------------------------------
__global__ void build_a(const float* __restrict__ Q, const float* __restrict__ S,
                        unsigned short* __restrict__ A) {
  int idx = blockIdx.x * 256 + threadIdx.x;         // one float4 per thread
  if (idx >= MROWS * 1024) return;
  int r    = idx >> 10;
  int rem  = idx & 1023;
  int seg  = rem >> 9;                              // 0: frame p0, 1: frame p1
  int k4   = (rem & 511) << 2;                      // element offset in segment
  int t;
  const float* base;
  if (r < NQT) {
    int n = r / 45; t = r - n * 45;
    base = Q + (size_t)n * (10 * 2048);
  } else {
    int rr = r - NQT;
    int c  = rr / 225; int j = rr - c * 225;
    int sh = j / 45;   t = j - sh * 45;
    base = S + (size_t)(c * 5 + sh) * (10 * 2048);
  }
  int frame = seg ? P1[t] : P0[t];
  float4 v = *reinterpret_cast<const float4*>(base + frame * 2048 + k4);
  ushort4 o;
  o.x = f2b(v.x); o.y = f2b(v.y); o.z = f2b(v.z); o.w = f2b(v.w);
  *reinterpret_cast<ushort4*>(A + (size_t)r * 4096 + seg * 2048 + k4) = o;
}

// ---- 2/4: bf16 MFMA GEMM, C = A @ B^T, 128x128 tile, BK=32 -----------------
// epi==0: E[row*lde+col] = bf16(relu(acc + bias[col]))
// epi==1: Dout[row*ldd+col] = sqrt(max(0, sq[row] + sq[3375+col] - 2*acc))
__global__ __launch_bounds__(256)
void gemm_bt(const unsigned short* __restrict__ A, const unsigned short* __restrict__ B,
             int K, int lda, int ldb, int epi,
             const float* __restrict__ bias,
             unsigned short* __restrict__ E, int lde,
             const float* __restrict__ sq,
             float* __restrict__ Dout, int ldd) {
  __shared__ unsigned short As[128 * LDS_S];
  __shared__ unsigned short Bs[128 * LDS_S];
  const int tid  = threadIdx.x;
  const int wave = tid >> 6, lane = tid & 63;
  const int quad = lane >> 4, l16 = lane & 15;
  const int wm = (wave >> 1) * 64, wn = (wave & 1) * 64;
  const int m0 = blockIdx.x * 128, n0 = blockIdx.y * 128;

  f32x4 acc[4][4];
#pragma unroll
  for (int i = 0; i < 4; ++i)
#pragma unroll
    for (int j = 0; j < 4; ++j) {
      f32x4 z = {0.f, 0.f, 0.f, 0.f};
      acc[i][j] = z;
    }

  const int r0  = tid >> 2;          // 0..63
  const int kp0 = (tid & 3) * 8;     // 16B chunk within 32-elem row

  for (int k0 = 0; k0 < K; k0 += 32) {
    uint4 a0 = *reinterpret_cast<const uint4*>(A + (size_t)(m0 + r0) * lda + k0 + kp0);
    uint4 a1 = *reinterpret_cast<const uint4*>(A + (size_t)(m0 + r0 + 64) * lda + k0 + kp0);
    uint4 b0 = *reinterpret_cast<const uint4*>(B + (size_t)(n0 + r0) * ldb + k0 + kp0);
    uint4 b1 = *reinterpret_cast<const uint4*>(B + (size_t)(n0 + r0 + 64) * ldb + k0 + kp0);
    *reinterpret_cast<uint4*>(&As[r0 * LDS_S + kp0]) = a0;
    *reinterpret_cast<uint4*>(&As[(r0 + 64) * LDS_S + kp0]) = a1;
    *reinterpret_cast<uint4*>(&Bs[r0 * LDS_S + kp0]) = b0;
    *reinterpret_cast<uint4*>(&Bs[(r0 + 64) * LDS_S + kp0]) = b1;
    __syncthreads();
    bf16x8 af[4], bfr[4];
#pragma unroll
    for (int t = 0; t < 4; ++t)
      af[t] = *reinterpret_cast<const bf16x8*>(&As[(wm + t * 16 + l16) * LDS_S + quad * 8]);
#pragma unroll
    for (int t = 0; t < 4; ++t)
      bfr[t] = *reinterpret_cast<const bf16x8*>(&Bs[(wn + t * 16 + l16) * LDS_S + quad * 8]);
#pragma unroll
    for (int i = 0; i < 4; ++i)
#pragma unroll
      for (int j = 0; j < 4; ++j)
        acc[i][j] = __builtin_amdgcn_mfma_f32_16x16x32_bf16(af[i], bfr[j], acc[i][j], 0, 0, 0);
    __syncthreads();
  }

  // epilogue: C/D layout col=lane&15, row=quad*4+reg
  if (epi == 0) {
#pragma unroll
    for (int i = 0; i < 4; ++i)
#pragma unroll
      for (int j = 0; j < 4; ++j) {
        int col = n0 + wn + j * 16 + l16;
        int rbase = m0 + wm + i * 16 + quad * 4;
        float bv = bias[col];
        f32x4 v = acc[i][j];
#pragma unroll
        for (int r = 0; r < 4; ++r) {
          float x = v[r] + bv;
          x = fmaxf(x, 0.f);
          E[(size_t)(rbase + r) * lde + col] = f2b(x);
        }
      }
  } else {
#pragma unroll
    for (int i = 0; i < 4; ++i)
#pragma unroll
      for (int j = 0; j < 4; ++j) {
        int col = n0 + wn + j * 16 + l16;
        int rbase = m0 + wm + i * 16 + quad * 4;
        float sc = sq[NQT + col];
        f32x4 v = acc[i][j];
#pragma unroll
        for (int r = 0; r < 4; ++r) {
          float x = sq[rbase + r] + sc - 2.f * v[r];
          Dout[(size_t)(rbase + r) * ldd + col] = sqrtf(fmaxf(x, 0.f));
        }
      }
  }
}

// ---- 3: row squared-norms of E (bf16) --------------------------------------
__global__ void norm_rows(const unsigned short* __restrict__ E, float* __restrict__ sq) {
  int row = blockIdx.x, tid = threadIdx.x;
  uint4 v = reinterpret_cast<const uint4*>(E + (size_t)row * 2048)[tid];
  unsigned int w[4] = {v.x, v.y, v.z, v.w};
  float s = 0.f;
#pragma unroll
  for (int u = 0; u < 4; ++u) {
    float lo = __uint_as_float(w[u] << 16);
    float hi = __uint_as_float(w[u] & 0xffff0000u);
    s += lo * lo + hi * hi;
  }
  __shared__ float red[256];
  red[tid] = s;
  __syncthreads();
  for (int st = 128; st > 0; st >>= 1) {
    if (tid < st) red[tid] += red[tid + st];
    __syncthreads();
  }
  if (tid == 0) sq[row] = red[0];
}

// ---- 5: per (c,i) stats ----------------------------------------------------
__global__ void stats_kernel(const float* __restrict__ D, float* __restrict__ ave,
                             int* __restrict__ pos, float* __restrict__ rmax) {
  int gid = blockIdx.x * 256 + threadIdx.x;
  if (gid >= 5 * NQT) return;
  int c = gid / NQT, i = gid - c * NQT;
  const float* p = D + (size_t)i * LDD + c * 225;
  float best = -1e30f; int bi = 0;
  float gm[5] = {-1e30f, -1e30f, -1e30f, -1e30f, -1e30f};
  for (int tr = 0; tr < 45; ++tr) {
#pragma unroll
    for (int sr = 0; sr < 5; ++sr) {
      int j = tr * 5 + sr;
      float v = p[j];
      if (v > best) { best = v; bi = j; }     // first-occurrence argmax
      gm[sr] = fmaxf(gm[sr], v);
    }
  }
  ave[gid]  = (gm[0] + gm[1] + gm[2] + gm[3] + gm[4]) * 0.2f;
  pos[gid]  = bi;
  rmax[gid] = best;
}

// ---- 6: dist_max -----------------------------------------------------------
__global__ void dmax_kernel(const float* __restrict__ rmax, float* __restrict__ out,
                            float* __restrict__ dmaxbuf) {
  int gid = blockIdx.x * 256 + threadIdx.x;
  if (gid >= 375) return;
  int q = gid / 5, c = gid - q * 5;
  float s = 0.f;
  for (int t = 0; t < 45; ++t) s += rmax[c * NQT + q * 45 + t];
  float v = s / 45.f;
  out[q * 5 + c] = v;
  dmaxbuf[q * 5 + c] = v;
}

// ---- 7: record + mask per (c, other-class) ---------------------------------
__global__ void record_kernel(const float* __restrict__ D, const float* __restrict__ ave,
                              const int* __restrict__ pos, float* __restrict__ mask) {
  int b = blockIdx.x;                 // 0..19
  int c = b / 4, mi = b - c * 4;
  int mm = mi + (mi >= c ? 1 : 0);
  int tid = threadIdx.x;
  float cnt = 0.f;
  if (tid < 225) {
    const float* base = D + (size_t)(NQT + c * 225) * LDD + mm * 225 + tid;
    for (int i = 0; i < NQT; ++i) {
      int p  = pos[c * NQT + i];
      float a = ave[c * NQT + i];
      float v = base[(size_t)p * LDD];
      cnt += (v > a) ? 1.f : 0.f;
    }
  }
  __shared__ float rec[256];
  __shared__ float thr_s;
  rec[tid] = (tid < 225) ? cnt : 0.f;
  __syncthreads();
  if (tid == 0) {
    float ssum = 0.f, nz = 0.f;
    for (int j = 0; j < 225; ++j) { ssum += rec[j]; if (rec[j] != 0.f) nz += 1.f; }
    if (nz < 1.f) nz = 1.f;
    thr_s = ssum / nz;
  }
  __syncthreads();
  if (tid < 225) mask[(c * 4 + mi) * 225 + tid] = (rec[tid] < thr_s) ? 1.f : 0.f;
}

// ---- 8: masked-mean contrast + logits --------------------------------------
__global__ void contrast_kernel(const float* __restrict__ D, const float* __restrict__ mask,
                                const float* __restrict__ dmaxbuf, float* __restrict__ out) {
  int b = blockIdx.x;                 // 0..374
  int q = b / 5, c = b - q * 5;
  int tid = threadIdx.x;
  __shared__ float red[256];
  // msum for class c
  float ms = 0.f;
  for (int e = tid; e < 900; e += 256) ms += mask[c * 900 + e];
  red[tid] = ms;
  __syncthreads();
  for (int st = 128; st > 0; st >>= 1) {
    if (tid < st) red[tid] += red[tid + st];
    __syncthreads();
  }
  float msum = red[0];
  if (msum < 1.f) msum = 1.f;
  __syncthreads();
  float acc = 0.f;
  for (int e = tid; e < 45 * 900; e += 256) {
    int t = e / 900, rest = e - t * 900;
    int mi = rest / 225, s2 = rest - mi * 225;
    int mm = mi + (mi >= c ? 1 : 0);
    float m = mask[c * 900 + rest];
    if (m != 0.f)
      acc += D[(size_t)(q * 45 + t) * LDD + mm * 225 + s2];
  }
  red[tid] = acc;
  __syncthreads();
  for (int st = 128; st > 0; st >>= 1) {
    if (tid < st) red[tid] += red[tid + st];
    __syncthreads();
  }
  if (tid == 0) {
    float contrast = red[0] / (msum * 180.f);   // /msum /45 /(WAY-1)
    float dm = dmaxbuf[q * 5 + c];
    out[375 + q * 5 + c] = dm / (contrast + dm);
  }
}

// ---------------------------------------------------------------------------
extern "C" void kernel_launch(void* const* d_in, const int* in_sizes, int n_in,
                              void* d_out, int out_size, void* d_ws, size_t ws_size,
                              hipStream_t stream) {
  const float* support = (const float*)d_in[0];
  // d_in[1] = support_labels (arange//SHOT) -- class gather is a reshape, unused
  const float* queries = (const float*)d_in[2];
  const float* W       = (const float*)d_in[3];
  const float* bias    = (const float*)d_in[4];
  float* out = (float*)d_out;

  char* ws = (char*)d_ws;
  size_t off = 0;
  unsigned short* Wb = (unsigned short*)(ws + off); off += (size_t)2048 * 4096 * 2;   // 16,777,216
  unsigned short* Ab = (unsigned short*)(ws + off);
  float*          Dm = (float*)(ws + off);          off += (size_t)MPAD * 4096 * 2;   // 37,748,736 (A, reused as D)
  unsigned short* Eb = (unsigned short*)(ws + off); off += (size_t)MPAD * 2048 * 2;   // 18,874,368
  float* sq      = (float*)(ws + off); off += 4608 * 4 + 256;
  float* ave     = (float*)(ws + off); off += 5 * NQT * 4 + 256;
  int*   pos     = (int*)(ws + off);   off += 5 * NQT * 4 + 256;
  float* rmax    = (float*)(ws + off); off += 5 * NQT * 4 + 256;
  float* mask    = (float*)(ws + off); off += 5 * 4 * 225 * 4 + 256;
  float* dmaxbuf = (float*)(ws + off); off += 375 * 4 + 256;

  conv_w<<<(2048 * 4096 / 4) / 256, 256, 0, stream>>>(W, Wb);
  build_a<<<(MROWS * 1024) / 256, 256, 0, stream>>>(queries, support, Ab);

  dim3 g1(MPAD / 128, N1 / 128);   // 36 x 16
  gemm_bt<<<g1, 256, 0, stream>>>(Ab, Wb, K1, K1, K1, 0, bias, Eb, N1,
                                  nullptr, nullptr, 0);

  norm_rows<<<MPAD, 256, 0, stream>>>(Eb, sq);

  dim3 g2(MPAD / 128, LDD / 128);  // 36 x 9
  gemm_bt<<<g2, 256, 0, stream>>>(Eb, Eb + (size_t)NQT * 2048, K2, K2, K2, 1,
                                  nullptr, nullptr, 0, sq, Dm, LDD);

  stats_kernel<<<(5 * NQT + 255) / 256, 256, 0, stream>>>(Dm, ave, pos, rmax);
  dmax_kernel<<<2, 256, 0, stream>>>(rmax, out, dmaxbuf);
  record_kernel<<<20, 256, 0, stream>>>(Dm, ave, pos, mask);
  contrast_kernel<<<375, 256, 0, stream>>>(Dm, mask, dmaxbuf, out);
}

// Round 2
// 491.743 us; speedup vs baseline: 1.4730x; 1.4730x over previous
//
#include <hip/hip_runtime.h>

// ---------------------------------------------------------------------------
// DistanceLoss pipeline on MI355X (gfx950)
//  0. convert clsW_w fp32 -> bf16                  (conv_w)
//  1. tuple-gather queries+supports -> A bf16      (build_a)
//  2. E = relu(A @ W^T + b)  [4608 x 2048] bf16    (gemm_bt epi=0, m97 lds)
//  3. sq[i] = |E[i]|^2                             (norm_rows)
//  4. D[i][j] = dist(E[i], E[3375+j]) [4608x1152]  (gemm_bt epi=1)
//  5. per-(c,i): rowmax/argmax/group-max stats     (stats_kernel)
//  6. dist_max reduce -> out[0:375]                (dmax_kernel)
//  7a. record counts, class x 900 cols             (record_part, 135 blocks)
//  7b. thr + mask                                  (record_finish)
//  8. masked-mean contrast -> out[375:750]         (contrast_kernel)
// ---------------------------------------------------------------------------

typedef __bf16 bf16x8 __attribute__((ext_vector_type(8)));
typedef float f32x4 __attribute__((ext_vector_type(4)));

#define NQT   3375      // 75*45 query-tuple rows
#define MROWS 4500      // 3375 query rows + 1125 support rows
#define MPAD  4608      // 36 * 128
#define K1    4096
#define N1    2048
#define K2    2048
#define LDD   1152      // padded 1125 -> 9*128
#define BK    32        // K-tile; LDS stride = 32 (UNPADDED: required by global_load_lds)

__constant__ int P0[45] = {0,0,0,0,0,0,0,0,0,
                           1,1,1,1,1,1,1,1,
                           2,2,2,2,2,2,2,
                           3,3,3,3,3,3,
                           4,4,4,4,4,
                           5,5,5,5,
                           6,6,6,
                           7,7,
                           8};
__constant__ int P1[45] = {1,2,3,4,5,6,7,8,9,
                           2,3,4,5,6,7,8,9,
                           3,4,5,6,7,8,9,
                           4,5,6,7,8,9,
                           5,6,7,8,9,
                           6,7,8,9,
                           7,8,9,
                           8,9,
                           9};

__device__ inline unsigned short f2b(float x) {
  __bf16 b = (__bf16)x;               // RNE
  return __builtin_bit_cast(unsigned short, b);
}

// async global->LDS, 16B per lane; lds dest must be wave-uniform base + lane*16
__device__ __forceinline__ void gl_lds16(const unsigned short* g, unsigned short* l) {
  __builtin_amdgcn_global_load_lds(
      (__attribute__((address_space(1))) void*)(g),
      (__attribute__((address_space(3))) void*)(l),
      16, 0, 0);
}

// ---- 0: W fp32 -> bf16 -----------------------------------------------------
__global__ void conv_w(const float* __restrict__ W, unsigned short* __restrict__ Wb) {
  int i = blockIdx.x * 256 + threadIdx.x;           // one float4 per thread
  if (i >= (2048 * 4096) / 4) return;
  float4 v = reinterpret_cast<const float4*>(W)[i];
  ushort4 o;
  o.x = f2b(v.x); o.y = f2b(v.y); o.z = f2b(v.z); o.w = f2b(v.w);
  reinterpret_cast<ushort4*>(Wb)[i] = o;
}

__global__ void zero_buf(float* __restrict__ p, int n) {
  int i = blockIdx.x * 256 + threadIdx.x;
  if (i < n) p[i] = 0.f;
}

// ---- 1: tuple gather -> A [MROWS x 4096] bf16 ------------------------------
__global__ void build_a(const float* __restrict__ Q, const float* __restrict__ S,
                        unsigned short* __restrict__ A) {
  int idx = blockIdx.x * 256 + threadIdx.x;         // one float4 per thread
  if (idx >= MROWS * 1024) return;
  int r    = idx >> 10;
  int rem  = idx & 1023;
  int seg  = rem >> 9;                              // 0: frame p0, 1: frame p1
  int k4   = (rem & 511) << 2;                      // element offset in segment
  int t;
  const float* base;
  if (r < NQT) {
    int n = r / 45; t = r - n * 45;
    base = Q + (size_t)n * (10 * 2048);
  } else {
    int rr = r - NQT;
    int c  = rr / 225; int j = rr - c * 225;
    int sh = j / 45;   t = j - sh * 45;
    base = S + (size_t)(c * 5 + sh) * (10 * 2048);
  }
  int frame = seg ? P1[t] : P0[t];
  float4 v = *reinterpret_cast<const float4*>(base + frame * 2048 + k4);
  ushort4 o;
  o.x = f2b(v.x); o.y = f2b(v.y); o.z = f2b(v.z); o.w = f2b(v.w);
  *reinterpret_cast<ushort4*>(A + (size_t)r * 4096 + seg * 2048 + k4) = o;
}

// ---- 2/4: bf16 MFMA GEMM, C = A @ B^T, 128x128 tile, BK=32, global_load_lds
// epi==0: E[row*lde+col] = bf16(relu(acc + bias[col]))
// epi==1: Dout[row*ldd+col] = sqrt(max(0, sq[row] + sq[3375+col] - 2*acc))
__global__ __launch_bounds__(256)
void gemm_bt(const unsigned short* __restrict__ A, const unsigned short* __restrict__ B,
             int K, int lda, int ldb, int epi,
             const float* __restrict__ bias,
             unsigned short* __restrict__ E, int lde,
             const float* __restrict__ sq,
             float* __restrict__ Dout, int ldd) {
  __shared__ unsigned short As[128 * BK];   // 8 KB, stride 32 (no pad)
  __shared__ unsigned short Bs[128 * BK];
  const int tid  = threadIdx.x;
  const int wave = tid >> 6, lane = tid & 63;
  const int quad = lane >> 4, l16 = lane & 15;
  const int wm = (wave >> 1) * 64, wn = (wave & 1) * 64;
  const int m0 = blockIdx.x * 128, n0 = blockIdx.y * 128;

  f32x4 acc[4][4];
#pragma unroll
  for (int i = 0; i < 4; ++i)
#pragma unroll
    for (int j = 0; j < 4; ++j) {
      f32x4 z = {0.f, 0.f, 0.f, 0.f};
      acc[i][j] = z;
    }

  const int r0  = tid >> 2;          // 0..63
  const int kp0 = (tid & 3) * 8;     // 16B chunk within 32-elem row
  // LDS dest for global_load_lds: wave-uniform base; lanes land at +lane*16
  unsigned short* lA0 = &As[wave * 512];
  unsigned short* lA1 = &As[2048 + wave * 512];
  unsigned short* lB0 = &Bs[wave * 512];
  unsigned short* lB1 = &Bs[2048 + wave * 512];
  const unsigned short* pa0 = A + (size_t)(m0 + r0) * lda + kp0;
  const unsigned short* pa1 = A + (size_t)(m0 + r0 + 64) * lda + kp0;
  const unsigned short* pb0 = B + (size_t)(n0 + r0) * ldb + kp0;
  const unsigned short* pb1 = B + (size_t)(n0 + r0 + 64) * ldb + kp0;

  for (int k0 = 0; k0 < K; k0 += BK) {
    gl_lds16(pa0, lA0);
    gl_lds16(pa1, lA1);
    gl_lds16(pb0, lB0);
    gl_lds16(pb1, lB1);
    pa0 += BK; pa1 += BK; pb0 += BK; pb1 += BK;
    __syncthreads();   // drains vmcnt -> LDS tiles complete
    bf16x8 af[4], bfr[4];
#pragma unroll
    for (int t = 0; t < 4; ++t)
      af[t] = *reinterpret_cast<const bf16x8*>(&As[(wm + t * 16 + l16) * BK + quad * 8]);
#pragma unroll
    for (int t = 0; t < 4; ++t)
      bfr[t] = *reinterpret_cast<const bf16x8*>(&Bs[(wn + t * 16 + l16) * BK + quad * 8]);
#pragma unroll
    for (int i = 0; i < 4; ++i)
#pragma unroll
      for (int j = 0; j < 4; ++j)
        acc[i][j] = __builtin_amdgcn_mfma_f32_16x16x32_bf16(af[i], bfr[j], acc[i][j], 0, 0, 0);
    __syncthreads();
  }

  // epilogue: C/D layout col=lane&15, row=quad*4+reg
  if (epi == 0) {
#pragma unroll
    for (int i = 0; i < 4; ++i)
#pragma unroll
      for (int j = 0; j < 4; ++j) {
        int col = n0 + wn + j * 16 + l16;
        int rbase = m0 + wm + i * 16 + quad * 4;
        float bv = bias[col];
        f32x4 v = acc[i][j];
#pragma unroll
        for (int r = 0; r < 4; ++r) {
          float x = v[r] + bv;
          x = fmaxf(x, 0.f);
          E[(size_t)(rbase + r) * lde + col] = f2b(x);
        }
      }
  } else {
#pragma unroll
    for (int i = 0; i < 4; ++i)
#pragma unroll
      for (int j = 0; j < 4; ++j) {
        int col = n0 + wn + j * 16 + l16;
        int rbase = m0 + wm + i * 16 + quad * 4;
        float sc = sq[NQT + col];
        f32x4 v = acc[i][j];
#pragma unroll
        for (int r = 0; r < 4; ++r) {
          float x = sq[rbase + r] + sc - 2.f * v[r];
          Dout[(size_t)(rbase + r) * ldd + col] = sqrtf(fmaxf(x, 0.f));
        }
      }
  }
}

// ---- 3: row squared-norms of E (bf16) --------------------------------------
__global__ void norm_rows(const unsigned short* __restrict__ E, float* __restrict__ sq) {
  int row = blockIdx.x, tid = threadIdx.x;
  uint4 v = reinterpret_cast<const uint4*>(E + (size_t)row * 2048)[tid];
  unsigned int w[4] = {v.x, v.y, v.z, v.w};
  float s = 0.f;
#pragma unroll
  for (int u = 0; u < 4; ++u) {
    float lo = __uint_as_float(w[u] << 16);
    float hi = __uint_as_float(w[u] & 0xffff0000u);
    s += lo * lo + hi * hi;
  }
  __shared__ float red[256];
  red[tid] = s;
  __syncthreads();
  for (int st = 128; st > 0; st >>= 1) {
    if (tid < st) red[tid] += red[tid + st];
    __syncthreads();
  }
  if (tid == 0) sq[row] = red[0];
}

// ---- 5: per (c,i) stats ----------------------------------------------------
__global__ void stats_kernel(const float* __restrict__ D, float* __restrict__ ave,
                             int* __restrict__ pos, float* __restrict__ rmax) {
  int gid = blockIdx.x * 256 + threadIdx.x;
  if (gid >= 5 * NQT) return;
  int c = gid / NQT, i = gid - c * NQT;
  const float* p = D + (size_t)i * LDD + c * 225;
  float best = -1e30f; int bi = 0;
  float gm[5] = {-1e30f, -1e30f, -1e30f, -1e30f, -1e30f};
  for (int tr = 0; tr < 45; ++tr) {
#pragma unroll
    for (int sr = 0; sr < 5; ++sr) {
      int j = tr * 5 + sr;
      float v = p[j];
      if (v > best) { best = v; bi = j; }     // first-occurrence argmax
      gm[sr] = fmaxf(gm[sr], v);
    }
  }
  ave[gid]  = (gm[0] + gm[1] + gm[2] + gm[3] + gm[4]) * 0.2f;
  pos[gid]  = bi;
  rmax[gid] = best;
}

// ---- 6: dist_max -----------------------------------------------------------
__global__ void dmax_kernel(const float* __restrict__ rmax, float* __restrict__ out,
                            float* __restrict__ dmaxbuf) {
  int gid = blockIdx.x * 256 + threadIdx.x;
  if (gid >= 375) return;
  int q = gid / 5, c = gid - q * 5;
  float s = 0.f;
  for (int t = 0; t < 45; ++t) s += rmax[c * NQT + q * 45 + t];
  float v = s / 45.f;
  out[q * 5 + c] = v;
  dmaxbuf[q * 5 + c] = v;
}

// ---- 7a: record counts, parallel over query chunks -------------------------
// grid = 5 classes * 27 chunks of 125 queries; record[c][col], col in [0,900)
__global__ void record_part(const float* __restrict__ D, const float* __restrict__ ave,
                            const int* __restrict__ pos, float* __restrict__ record) {
  int b = blockIdx.x;
  int c = b / 27, chunk = b - c * 27;
  int i0 = chunk * 125;
  int tid = threadIdx.x;
  __shared__ int   sp[125];
  __shared__ float sa[125];
  if (tid < 125) {
    sp[tid] = pos[c * NQT + i0 + tid];
    sa[tid] = ave[c * NQT + i0 + tid];
  }
  __syncthreads();
  // thread owns columns tid, tid+256, tid+512, tid+768 (those < 900)
  float cnt[4] = {0.f, 0.f, 0.f, 0.f};
  int gcol[4];
#pragma unroll
  for (int j = 0; j < 4; ++j) {
    int col = tid + j * 256;
    gcol[j] = (col < 900) ? (col < c * 225 ? col : col + 225) : 0;
  }
  const bool act3 = (tid + 768) < 900;
  const float* Dsup = D + (size_t)(NQT + c * 225) * LDD;
  for (int ii = 0; ii < 125; ++ii) {
    const float* row = Dsup + (size_t)sp[ii] * LDD;
    float a = sa[ii];
    cnt[0] += (row[gcol[0]] > a) ? 1.f : 0.f;
    cnt[1] += (row[gcol[1]] > a) ? 1.f : 0.f;
    cnt[2] += (row[gcol[2]] > a) ? 1.f : 0.f;
    if (act3) cnt[3] += (row[gcol[3]] > a) ? 1.f : 0.f;
  }
#pragma unroll
  for (int j = 0; j < 4; ++j) {
    int col = tid + j * 256;
    if (col < 900) atomicAdd(&record[c * 900 + col], cnt[j]);
  }
}

// ---- 7b: thr + mask --------------------------------------------------------
__global__ void record_finish(const float* __restrict__ record, float* __restrict__ mask) {
  int b = blockIdx.x;                 // 0..19
  int c = b / 4, mi = b - c * 4;
  int tid = threadIdx.x;
  float r = (tid < 225) ? record[c * 900 + mi * 225 + tid] : 0.f;
  __shared__ float s1[256], s2[256];
  __shared__ float thr_s;
  s1[tid] = r;
  s2[tid] = (tid < 225 && r != 0.f) ? 1.f : 0.f;
  __syncthreads();
  for (int st = 128; st > 0; st >>= 1) {
    if (tid < st) { s1[tid] += s1[tid + st]; s2[tid] += s2[tid + st]; }
    __syncthreads();
  }
  if (tid == 0) {
    float nz = s2[0] < 1.f ? 1.f : s2[0];
    thr_s = s1[0] / nz;
  }
  __syncthreads();
  if (tid < 225) mask[(c * 4 + mi) * 225 + tid] = (r < thr_s) ? 1.f : 0.f;
}

// ---- 8: masked-mean contrast + logits --------------------------------------
__global__ void contrast_kernel(const float* __restrict__ D, const float* __restrict__ mask,
                                const float* __restrict__ dmaxbuf, float* __restrict__ out) {
  int b = blockIdx.x;                 // 0..374
  int q = b / 5, c = b - q * 5;
  int tid = threadIdx.x;
  __shared__ float red[256];
  // msum for class c
  float ms = 0.f;
  for (int e = tid; e < 900; e += 256) ms += mask[c * 900 + e];
  red[tid] = ms;
  __syncthreads();
  for (int st = 128; st > 0; st >>= 1) {
    if (tid < st) red[tid] += red[tid + st];
    __syncthreads();
  }
  float msum = red[0];
  if (msum < 1.f) msum = 1.f;
  __syncthreads();
  float acc = 0.f;
  for (int e = tid; e < 45 * 900; e += 256) {
    int t = e / 900, rest = e - t * 900;
    int mi = rest / 225, s2 = rest - mi * 225;
    int mm = mi + (mi >= c ? 1 : 0);
    float m = mask[c * 900 + rest];
    if (m != 0.f)
      acc += D[(size_t)(q * 45 + t) * LDD + mm * 225 + s2];
  }
  red[tid] = acc;
  __syncthreads();
  for (int st = 128; st > 0; st >>= 1) {
    if (tid < st) red[tid] += red[tid + st];
    __syncthreads();
  }
  if (tid == 0) {
    float contrast = red[0] / (msum * 180.f);   // /msum /45 /(WAY-1)
    float dm = dmaxbuf[q * 5 + c];
    out[375 + q * 5 + c] = dm / (contrast + dm);
  }
}

// ---------------------------------------------------------------------------
extern "C" void kernel_launch(void* const* d_in, const int* in_sizes, int n_in,
                              void* d_out, int out_size, void* d_ws, size_t ws_size,
                              hipStream_t stream) {
  const float* support = (const float*)d_in[0];
  // d_in[1] = support_labels (arange//SHOT) -- class gather is a reshape, unused
  const float* queries = (const float*)d_in[2];
  const float* W       = (const float*)d_in[3];
  const float* bias    = (const float*)d_in[4];
  float* out = (float*)d_out;

  char* ws = (char*)d_ws;
  size_t off = 0;
  unsigned short* Wb = (unsigned short*)(ws + off); off += (size_t)2048 * 4096 * 2;
  unsigned short* Ab = (unsigned short*)(ws + off);
  float*          Dm = (float*)(ws + off);          off += (size_t)MPAD * 4096 * 2;  // A, reused as D
  unsigned short* Eb = (unsigned short*)(ws + off); off += (size_t)MPAD * 2048 * 2;
  float* sq      = (float*)(ws + off); off += 4608 * 4 + 256;
  float* ave     = (float*)(ws + off); off += 5 * NQT * 4 + 256;
  int*   pos     = (int*)(ws + off);   off += 5 * NQT * 4 + 256;
  float* rmax    = (float*)(ws + off); off += 5 * NQT * 4 + 256;
  float* mask    = (float*)(ws + off); off += 5 * 4 * 225 * 4 + 256;
  float* dmaxbuf = (float*)(ws + off); off += 375 * 4 + 256;
  float* record  = (float*)(ws + off); off += 5 * 900 * 4 + 256;

  conv_w<<<(2048 * 4096 / 4) / 256, 256, 0, stream>>>(W, Wb);
  zero_buf<<<(5 * 900 + 255) / 256, 256, 0, stream>>>(record, 5 * 900);
  build_a<<<(MROWS * 1024) / 256, 256, 0, stream>>>(queries, support, Ab);

  dim3 g1(MPAD / 128, N1 / 128);   // 36 x 16
  gemm_bt<<<g1, 256, 0, stream>>>(Ab, Wb, K1, K1, K1, 0, bias, Eb, N1,
                                  nullptr, nullptr, 0);

  norm_rows<<<MPAD, 256, 0, stream>>>(Eb, sq);

  dim3 g2(MPAD / 128, LDD / 128);  // 36 x 9
  gemm_bt<<<g2, 256, 0, stream>>>(Eb, Eb + (size_t)NQT * 2048, K2, K2, K2, 1,
                                  nullptr, nullptr, 0, sq, Dm, LDD);

  stats_kernel<<<(5 * NQT + 255) / 256, 256, 0, stream>>>(Dm, ave, pos, rmax);
  dmax_kernel<<<2, 256, 0, stream>>>(rmax, out, dmaxbuf);
  record_part<<<135, 256, 0, stream>>>(Dm, ave, pos, record);
  record_finish<<<20, 256, 0, stream>>>(record, mask);
  contrast_kernel<<<375, 256, 0, stream>>>(Dm, mask, dmaxbuf, out);
}

// Round 3
// 483.604 us; speedup vs baseline: 1.4978x; 1.0168x over previous
//
#include <hip/hip_runtime.h>

// ---------------------------------------------------------------------------
// DistanceLoss pipeline on MI355X (gfx950)
//  0. convert clsW_w fp32 -> bf16                  (conv_w)
//  1. tuple-gather queries+supports -> A bf16      (build_a)
//  2. E = relu(A @ W^T + b)  [4608 x 2048] bf16    (gemm_bt epi=0, m97 lds)
//  3. sq[i] = |E[i]|^2                             (norm_rows)
//  4. D[i][j] = dist(E[i], E[3375+j]) [4608x1152]  (gemm_bt epi=1)
//  5. per-(c,i): rowmax/argmax/group-max stats     (stats_kernel)
//  6. dist_max reduce -> out[0:375]                (dmax_kernel)
//  7a. record counts, class x 900 cols             (record_part, 135 blocks)
//  7b. thr + mask                                  (record_finish)
//  8. masked-mean contrast -> out[375:750]         (contrast_kernel)
//
// GEMM LDS layout: global_load_lds forces row-major stride-32 (64B rows, no
// pad). To kill the 8-way ds_read_b128 bank conflict, LDS slot (row, s)
// holds global chunk q = s ^ ((row>>1)&3)  (chunk = 8 bf16 = 16B).
//  - write: lane fetches global chunk (tid&3)^((tid>>3)&3)
//  - read:  chunk `quad` of row base16+l16 is at slot quad^((l16>>1)&3)
// Resulting reads are uniform 2-way (free, m136).
// ---------------------------------------------------------------------------

typedef __bf16 bf16x8 __attribute__((ext_vector_type(8)));
typedef float f32x4 __attribute__((ext_vector_type(4)));

#define NQT   3375      // 75*45 query-tuple rows
#define MROWS 4500      // 3375 query rows + 1125 support rows
#define MPAD  4608      // 36 * 128
#define K1    4096
#define N1    2048
#define K2    2048
#define LDD   1152      // padded 1125 -> 9*128
#define BK    32        // K-tile; LDS stride = 32 (UNPADDED: required by global_load_lds)

__constant__ int P0[45] = {0,0,0,0,0,0,0,0,0,
                           1,1,1,1,1,1,1,1,
                           2,2,2,2,2,2,2,
                           3,3,3,3,3,3,
                           4,4,4,4,4,
                           5,5,5,5,
                           6,6,6,
                           7,7,
                           8};
__constant__ int P1[45] = {1,2,3,4,5,6,7,8,9,
                           2,3,4,5,6,7,8,9,
                           3,4,5,6,7,8,9,
                           4,5,6,7,8,9,
                           5,6,7,8,9,
                           6,7,8,9,
                           7,8,9,
                           8,9,
                           9};

__device__ inline unsigned short f2b(float x) {
  __bf16 b = (__bf16)x;               // RNE
  return __builtin_bit_cast(unsigned short, b);
}

// async global->LDS, 16B per lane; lds dest must be wave-uniform base + lane*16
__device__ __forceinline__ void gl_lds16(const unsigned short* g, unsigned short* l) {
  __builtin_amdgcn_global_load_lds(
      (__attribute__((address_space(1))) void*)(g),
      (__attribute__((address_space(3))) void*)(l),
      16, 0, 0);
}

// ---- 0: W fp32 -> bf16 -----------------------------------------------------
__global__ void conv_w(const float* __restrict__ W, unsigned short* __restrict__ Wb) {
  int i = blockIdx.x * 256 + threadIdx.x;           // one float4 per thread
  if (i >= (2048 * 4096) / 4) return;
  float4 v = reinterpret_cast<const float4*>(W)[i];
  ushort4 o;
  o.x = f2b(v.x); o.y = f2b(v.y); o.z = f2b(v.z); o.w = f2b(v.w);
  reinterpret_cast<ushort4*>(Wb)[i] = o;
}

__global__ void zero_buf(float* __restrict__ p, int n) {
  int i = blockIdx.x * 256 + threadIdx.x;
  if (i < n) p[i] = 0.f;
}

// ---- 1: tuple gather -> A [MROWS x 4096] bf16 ------------------------------
__global__ void build_a(const float* __restrict__ Q, const float* __restrict__ S,
                        unsigned short* __restrict__ A) {
  int idx = blockIdx.x * 256 + threadIdx.x;         // one float4 per thread
  if (idx >= MROWS * 1024) return;
  int r    = idx >> 10;
  int rem  = idx & 1023;
  int seg  = rem >> 9;                              // 0: frame p0, 1: frame p1
  int k4   = (rem & 511) << 2;                      // element offset in segment
  int t;
  const float* base;
  if (r < NQT) {
    int n = r / 45; t = r - n * 45;
    base = Q + (size_t)n * (10 * 2048);
  } else {
    int rr = r - NQT;
    int c  = rr / 225; int j = rr - c * 225;
    int sh = j / 45;   t = j - sh * 45;
    base = S + (size_t)(c * 5 + sh) * (10 * 2048);
  }
  int frame = seg ? P1[t] : P0[t];
  float4 v = *reinterpret_cast<const float4*>(base + frame * 2048 + k4);
  ushort4 o;
  o.x = f2b(v.x); o.y = f2b(v.y); o.z = f2b(v.z); o.w = f2b(v.w);
  *reinterpret_cast<ushort4*>(A + (size_t)r * 4096 + seg * 2048 + k4) = o;
}

// ---- 2/4: bf16 MFMA GEMM, C = A @ B^T, 128x128 tile, BK=32, global_load_lds
// epi==0: E[row*lde+col] = bf16(relu(acc + bias[col]))
// epi==1: Dout[row*ldd+col] = sqrt(max(0, sq[row] + sq[3375+col] - 2*acc))
__global__ __launch_bounds__(256)
void gemm_bt(const unsigned short* __restrict__ A, const unsigned short* __restrict__ B,
             int K, int lda, int ldb, int epi,
             const float* __restrict__ bias,
             unsigned short* __restrict__ E, int lde,
             const float* __restrict__ sq,
             float* __restrict__ Dout, int ldd) {
  __shared__ unsigned short As[128 * BK];   // 8 KB, stride 32 (no pad)
  __shared__ unsigned short Bs[128 * BK];
  const int tid  = threadIdx.x;
  const int wave = tid >> 6, lane = tid & 63;
  const int quad = lane >> 4, l16 = lane & 15;
  const int wm = (wave >> 1) * 64, wn = (wave & 1) * 64;
  const int m0 = blockIdx.x * 128, n0 = blockIdx.y * 128;

  f32x4 acc[4][4];
#pragma unroll
  for (int i = 0; i < 4; ++i)
#pragma unroll
    for (int j = 0; j < 4; ++j) {
      f32x4 z = {0.f, 0.f, 0.f, 0.f};
      acc[i][j] = z;
    }

  const int r0  = tid >> 2;                          // 0..63
  const int qsw = (tid & 3) ^ ((tid >> 3) & 3);      // swizzled global chunk
  const int kp0 = qsw * 8;
  // LDS read slot for logical chunk `quad` of row base16+l16 (bank-conflict-free)
  const int rsw = (quad ^ ((l16 >> 1) & 3)) * 8;
  // LDS dest for global_load_lds: wave-uniform base; lanes land at +lane*16
  unsigned short* lA0 = &As[wave * 512];
  unsigned short* lA1 = &As[2048 + wave * 512];
  unsigned short* lB0 = &Bs[wave * 512];
  unsigned short* lB1 = &Bs[2048 + wave * 512];
  const unsigned short* pa0 = A + (size_t)(m0 + r0) * lda + kp0;
  const unsigned short* pa1 = A + (size_t)(m0 + r0 + 64) * lda + kp0;
  const unsigned short* pb0 = B + (size_t)(n0 + r0) * ldb + kp0;
  const unsigned short* pb1 = B + (size_t)(n0 + r0 + 64) * ldb + kp0;

  for (int k0 = 0; k0 < K; k0 += BK) {
    gl_lds16(pa0, lA0);
    gl_lds16(pa1, lA1);
    gl_lds16(pb0, lB0);
    gl_lds16(pb1, lB1);
    pa0 += BK; pa1 += BK; pb0 += BK; pb1 += BK;
    __syncthreads();   // drains vmcnt -> LDS tiles complete
    bf16x8 af[4], bfr[4];
#pragma unroll
    for (int t = 0; t < 4; ++t)
      af[t] = *reinterpret_cast<const bf16x8*>(&As[(wm + t * 16 + l16) * BK + rsw]);
#pragma unroll
    for (int t = 0; t < 4; ++t)
      bfr[t] = *reinterpret_cast<const bf16x8*>(&Bs[(wn + t * 16 + l16) * BK + rsw]);
#pragma unroll
    for (int i = 0; i < 4; ++i)
#pragma unroll
      for (int j = 0; j < 4; ++j)
        acc[i][j] = __builtin_amdgcn_mfma_f32_16x16x32_bf16(af[i], bfr[j], acc[i][j], 0, 0, 0);
    __syncthreads();
  }

  // epilogue: C/D layout col=lane&15, row=quad*4+reg
  if (epi == 0) {
#pragma unroll
    for (int i = 0; i < 4; ++i)
#pragma unroll
      for (int j = 0; j < 4; ++j) {
        int col = n0 + wn + j * 16 + l16;
        int rbase = m0 + wm + i * 16 + quad * 4;
        float bv = bias[col];
        f32x4 v = acc[i][j];
#pragma unroll
        for (int r = 0; r < 4; ++r) {
          float x = v[r] + bv;
          x = fmaxf(x, 0.f);
          E[(size_t)(rbase + r) * lde + col] = f2b(x);
        }
      }
  } else {
#pragma unroll
    for (int i = 0; i < 4; ++i)
#pragma unroll
      for (int j = 0; j < 4; ++j) {
        int col = n0 + wn + j * 16 + l16;
        int rbase = m0 + wm + i * 16 + quad * 4;
        float sc = sq[NQT + col];
        f32x4 v = acc[i][j];
#pragma unroll
        for (int r = 0; r < 4; ++r) {
          float x = sq[rbase + r] + sc - 2.f * v[r];
          Dout[(size_t)(rbase + r) * ldd + col] = sqrtf(fmaxf(x, 0.f));
        }
      }
  }
}

// ---- 3: row squared-norms of E (bf16) --------------------------------------
__global__ void norm_rows(const unsigned short* __restrict__ E, float* __restrict__ sq) {
  int row = blockIdx.x, tid = threadIdx.x;
  uint4 v = reinterpret_cast<const uint4*>(E + (size_t)row * 2048)[tid];
  unsigned int w[4] = {v.x, v.y, v.z, v.w};
  float s = 0.f;
#pragma unroll
  for (int u = 0; u < 4; ++u) {
    float lo = __uint_as_float(w[u] << 16);
    float hi = __uint_as_float(w[u] & 0xffff0000u);
    s += lo * lo + hi * hi;
  }
  __shared__ float red[256];
  red[tid] = s;
  __syncthreads();
  for (int st = 128; st > 0; st >>= 1) {
    if (tid < st) red[tid] += red[tid + st];
    __syncthreads();
  }
  if (tid == 0) sq[row] = red[0];
}

// ---- 5: per (c,i) stats ----------------------------------------------------
__global__ void stats_kernel(const float* __restrict__ D, float* __restrict__ ave,
                             int* __restrict__ pos, float* __restrict__ rmax) {
  int gid = blockIdx.x * 256 + threadIdx.x;
  if (gid >= 5 * NQT) return;
  int c = gid / NQT, i = gid - c * NQT;
  const float* p = D + (size_t)i * LDD + c * 225;
  float best = -1e30f; int bi = 0;
  float gm[5] = {-1e30f, -1e30f, -1e30f, -1e30f, -1e30f};
  for (int tr = 0; tr < 45; ++tr) {
#pragma unroll
    for (int sr = 0; sr < 5; ++sr) {
      int j = tr * 5 + sr;
      float v = p[j];
      if (v > best) { best = v; bi = j; }     // first-occurrence argmax
      gm[sr] = fmaxf(gm[sr], v);
    }
  }
  ave[gid]  = (gm[0] + gm[1] + gm[2] + gm[3] + gm[4]) * 0.2f;
  pos[gid]  = bi;
  rmax[gid] = best;
}

// ---- 6: dist_max -----------------------------------------------------------
__global__ void dmax_kernel(const float* __restrict__ rmax, float* __restrict__ out,
                            float* __restrict__ dmaxbuf) {
  int gid = blockIdx.x * 256 + threadIdx.x;
  if (gid >= 375) return;
  int q = gid / 5, c = gid - q * 5;
  float s = 0.f;
  for (int t = 0; t < 45; ++t) s += rmax[c * NQT + q * 45 + t];
  float v = s / 45.f;
  out[q * 5 + c] = v;
  dmaxbuf[q * 5 + c] = v;
}

// ---- 7a: record counts, parallel over query chunks -------------------------
// grid = 5 classes * 27 chunks of 125 queries; record[c][col], col in [0,900)
__global__ void record_part(const float* __restrict__ D, const float* __restrict__ ave,
                            const int* __restrict__ pos, float* __restrict__ record) {
  int b = blockIdx.x;
  int c = b / 27, chunk = b - c * 27;
  int i0 = chunk * 125;
  int tid = threadIdx.x;
  __shared__ int   sp[125];
  __shared__ float sa[125];
  if (tid < 125) {
    sp[tid] = pos[c * NQT + i0 + tid];
    sa[tid] = ave[c * NQT + i0 + tid];
  }
  __syncthreads();
  // thread owns columns tid, tid+256, tid+512, tid+768 (those < 900)
  float cnt[4] = {0.f, 0.f, 0.f, 0.f};
  int gcol[4];
#pragma unroll
  for (int j = 0; j < 4; ++j) {
    int col = tid + j * 256;
    gcol[j] = (col < 900) ? (col < c * 225 ? col : col + 225) : 0;
  }
  const bool act3 = (tid + 768) < 900;
  const float* Dsup = D + (size_t)(NQT + c * 225) * LDD;
  for (int ii = 0; ii < 125; ++ii) {
    const float* row = Dsup + (size_t)sp[ii] * LDD;
    float a = sa[ii];
    cnt[0] += (row[gcol[0]] > a) ? 1.f : 0.f;
    cnt[1] += (row[gcol[1]] > a) ? 1.f : 0.f;
    cnt[2] += (row[gcol[2]] > a) ? 1.f : 0.f;
    if (act3) cnt[3] += (row[gcol[3]] > a) ? 1.f : 0.f;
  }
#pragma unroll
  for (int j = 0; j < 4; ++j) {
    int col = tid + j * 256;
    if (col < 900) atomicAdd(&record[c * 900 + col], cnt[j]);
  }
}

// ---- 7b: thr + mask --------------------------------------------------------
__global__ void record_finish(const float* __restrict__ record, float* __restrict__ mask) {
  int b = blockIdx.x;                 // 0..19
  int c = b / 4, mi = b - c * 4;
  int tid = threadIdx.x;
  float r = (tid < 225) ? record[c * 900 + mi * 225 + tid] : 0.f;
  __shared__ float s1[256], s2[256];
  __shared__ float thr_s;
  s1[tid] = r;
  s2[tid] = (tid < 225 && r != 0.f) ? 1.f : 0.f;
  __syncthreads();
  for (int st = 128; st > 0; st >>= 1) {
    if (tid < st) { s1[tid] += s1[tid + st]; s2[tid] += s2[tid + st]; }
    __syncthreads();
  }
  if (tid == 0) {
    float nz = s2[0] < 1.f ? 1.f : s2[0];
    thr_s = s1[0] / nz;
  }
  __syncthreads();
  if (tid < 225) mask[(c * 4 + mi) * 225 + tid] = (r < thr_s) ? 1.f : 0.f;
}

// ---- 8: masked-mean contrast + logits --------------------------------------
__global__ void contrast_kernel(const float* __restrict__ D, const float* __restrict__ mask,
                                const float* __restrict__ dmaxbuf, float* __restrict__ out) {
  int b = blockIdx.x;                 // 0..374
  int q = b / 5, c = b - q * 5;
  int tid = threadIdx.x;
  __shared__ float red[256];
  // msum for class c
  float ms = 0.f;
  for (int e = tid; e < 900; e += 256) ms += mask[c * 900 + e];
  red[tid] = ms;
  __syncthreads();
  for (int st = 128; st > 0; st >>= 1) {
    if (tid < st) red[tid] += red[tid + st];
    __syncthreads();
  }
  float msum = red[0];
  if (msum < 1.f) msum = 1.f;
  __syncthreads();
  float acc = 0.f;
  for (int e = tid; e < 45 * 900; e += 256) {
    int t = e / 900, rest = e - t * 900;
    int mi = rest / 225, s2 = rest - mi * 225;
    int mm = mi + (mi >= c ? 1 : 0);
    float m = mask[c * 900 + rest];
    if (m != 0.f)
      acc += D[(size_t)(q * 45 + t) * LDD + mm * 225 + s2];
  }
  red[tid] = acc;
  __syncthreads();
  for (int st = 128; st > 0; st >>= 1) {
    if (tid < st) red[tid] += red[tid + st];
    __syncthreads();
  }
  if (tid == 0) {
    float contrast = red[0] / (msum * 180.f);   // /msum /45 /(WAY-1)
    float dm = dmaxbuf[q * 5 + c];
    out[375 + q * 5 + c] = dm / (contrast + dm);
  }
}

// ---------------------------------------------------------------------------
extern "C" void kernel_launch(void* const* d_in, const int* in_sizes, int n_in,
                              void* d_out, int out_size, void* d_ws, size_t ws_size,
                              hipStream_t stream) {
  const float* support = (const float*)d_in[0];
  // d_in[1] = support_labels (arange//SHOT) -- class gather is a reshape, unused
  const float* queries = (const float*)d_in[2];
  const float* W       = (const float*)d_in[3];
  const float* bias    = (const float*)d_in[4];
  float* out = (float*)d_out;

  char* ws = (char*)d_ws;
  size_t off = 0;
  unsigned short* Wb = (unsigned short*)(ws + off); off += (size_t)2048 * 4096 * 2;
  unsigned short* Ab = (unsigned short*)(ws + off);
  float*          Dm = (float*)(ws + off);          off += (size_t)MPAD * 4096 * 2;  // A, reused as D
  unsigned short* Eb = (unsigned short*)(ws + off); off += (size_t)MPAD * 2048 * 2;
  float* sq      = (float*)(ws + off); off += 4608 * 4 + 256;
  float* ave     = (float*)(ws + off); off += 5 * NQT * 4 + 256;
  int*   pos     = (int*)(ws + off);   off += 5 * NQT * 4 + 256;
  float* rmax    = (float*)(ws + off); off += 5 * NQT * 4 + 256;
  float* mask    = (float*)(ws + off); off += 5 * 4 * 225 * 4 + 256;
  float* dmaxbuf = (float*)(ws + off); off += 375 * 4 + 256;
  float* record  = (float*)(ws + off); off += 5 * 900 * 4 + 256;

  conv_w<<<(2048 * 4096 / 4) / 256, 256, 0, stream>>>(W, Wb);
  zero_buf<<<(5 * 900 + 255) / 256, 256, 0, stream>>>(record, 5 * 900);
  build_a<<<(MROWS * 1024) / 256, 256, 0, stream>>>(queries, support, Ab);

  dim3 g1(MPAD / 128, N1 / 128);   // 36 x 16
  gemm_bt<<<g1, 256, 0, stream>>>(Ab, Wb, K1, K1, K1, 0, bias, Eb, N1,
                                  nullptr, nullptr, 0);

  norm_rows<<<MPAD, 256, 0, stream>>>(Eb, sq);

  dim3 g2(MPAD / 128, LDD / 128);  // 36 x 9
  gemm_bt<<<g2, 256, 0, stream>>>(Eb, Eb + (size_t)NQT * 2048, K2, K2, K2, 1,
                                  nullptr, nullptr, 0, sq, Dm, LDD);

  stats_kernel<<<(5 * NQT + 255) / 256, 256, 0, stream>>>(Dm, ave, pos, rmax);
  dmax_kernel<<<2, 256, 0, stream>>>(rmax, out, dmaxbuf);
  record_part<<<135, 256, 0, stream>>>(Dm, ave, pos, record);
  record_finish<<<20, 256, 0, stream>>>(record, mask);
  contrast_kernel<<<375, 256, 0, stream>>>(Dm, mask, dmaxbuf, out);
}

// Round 4
// 360.419 us; speedup vs baseline: 2.0097x; 1.3418x over previous
//
#include <hip/hip_runtime.h>

// ---------------------------------------------------------------------------
// DistanceLoss pipeline on MI355X (gfx950)
//
// Key restructure (R4): the tuple gather duplicates each (sample,frame) row
// 9x. Instead of E = relu(gather(X)@W^T+b) at 77 GFLOP, compute
//   Y = X(1000x2048) @ Wsplit^T(4096x2048)   [16.8 GFLOP]
//   E[r,c] = relu(Y[x0(r),c] + Y[x1(r),2048+c] + b[c])  (gather-add, tiny)
// where Wsplit[j]=W[j,0:2048] for j<2048, =W[j-2048,2048:4096] else.
//
//  0a. conv_w2: W fp32 -> split bf16 [4096x2048]
//  0b. conv_x : queries||supports fp32 -> bf16 X [1024x2048] (pad rows zero)
//  1. gemm_bt epi=2: Y = X @ Wsplit^T, fp32 [1024x4096]
//  2. build_e: E rows (bf16) + row norms sq
//  3. gemm_bt epi=1: D[i][j] = dist(E[i],E[3375+j]) [4608x1152]
//  4. stats / dmax / record_part / record_finish / contrast (unchanged)
//
// GEMM: 128x128 tile, BK=32, global_load_lds(16B) staging, chunk-XOR swizzle
// (LDS slot (row,s) holds global chunk s^((row>>1)&3)) -> 2-way reads (free).
// ---------------------------------------------------------------------------

typedef __bf16 bf16x8 __attribute__((ext_vector_type(8)));
typedef float f32x4 __attribute__((ext_vector_type(4)));

#define NQT   3375      // 75*45 query-tuple rows
#define MROWS 4500      // 3375 query rows + 1125 support rows
#define MPAD  4608      // 36 * 128
#define K2    2048
#define LDD   1152      // padded 1125 -> 9*128
#define BK    32        // K-tile; LDS stride = 32 (UNPADDED: required by global_load_lds)

__constant__ int P0[45] = {0,0,0,0,0,0,0,0,0,
                           1,1,1,1,1,1,1,1,
                           2,2,2,2,2,2,2,
                           3,3,3,3,3,3,
                           4,4,4,4,4,
                           5,5,5,5,
                           6,6,6,
                           7,7,
                           8};
__constant__ int P1[45] = {1,2,3,4,5,6,7,8,9,
                           2,3,4,5,6,7,8,9,
                           3,4,5,6,7,8,9,
                           4,5,6,7,8,9,
                           5,6,7,8,9,
                           6,7,8,9,
                           7,8,9,
                           8,9,
                           9};

__device__ inline unsigned short f2b(float x) {
  __bf16 b = (__bf16)x;               // RNE
  return __builtin_bit_cast(unsigned short, b);
}
__device__ inline float b2f(unsigned int u16) {
  return __uint_as_float(u16 << 16);
}

// async global->LDS, 16B per lane; lds dest must be wave-uniform base + lane*16
__device__ __forceinline__ void gl_lds16(const unsigned short* g, unsigned short* l) {
  __builtin_amdgcn_global_load_lds(
      (__attribute__((address_space(1))) void*)(g),
      (__attribute__((address_space(3))) void*)(l),
      16, 0, 0);
}

// ---- 0a: W fp32 -> split bf16 [4096 x 2048] --------------------------------
// Wsplit[j,kk] = j<2048 ? W[j,kk] : W[j-2048, 2048+kk]
__global__ void conv_w2(const float* __restrict__ W, unsigned short* __restrict__ Ws) {
  int i = blockIdx.x * 256 + threadIdx.x;           // one float4 per thread
  if (i >= (2048 * 4096) / 4) return;
  int i4 = i << 2;
  int o  = i4 >> 12;            // row in W (4096 per row)
  int k  = i4 & 4095;
  int hf = k >> 11;             // which half of K
  int kk = k & 2047;
  float4 v = reinterpret_cast<const float4*>(W)[i];
  ushort4 u;
  u.x = f2b(v.x); u.y = f2b(v.y); u.z = f2b(v.z); u.w = f2b(v.w);
  *reinterpret_cast<ushort4*>(Ws + (size_t)(o + hf * 2048) * 2048 + kk) = u;
}

// ---- 0b: X = bf16(queries || supports), rows 1000..1023 zero ---------------
__global__ void conv_x(const float* __restrict__ Q, const float* __restrict__ S,
                       unsigned short* __restrict__ X) {
  int i = blockIdx.x * 256 + threadIdx.x;           // one float4 slot
  if (i >= (1024 * 2048) / 4) return;
  ushort4 u = {0, 0, 0, 0};
  if (i < 384000) {                                  // 750*2048/4
    float4 v = reinterpret_cast<const float4*>(Q)[i];
    u.x = f2b(v.x); u.y = f2b(v.y); u.z = f2b(v.z); u.w = f2b(v.w);
  } else if (i < 512000) {                           // + 250*2048/4
    float4 v = reinterpret_cast<const float4*>(S)[i - 384000];
    u.x = f2b(v.x); u.y = f2b(v.y); u.z = f2b(v.z); u.w = f2b(v.w);
  }
  reinterpret_cast<ushort4*>(X)[i] = u;
}

__global__ void zero_buf(float* __restrict__ p, int n) {
  int i = blockIdx.x * 256 + threadIdx.x;
  if (i < n) p[i] = 0.f;
}

// ---- 1/3: bf16 MFMA GEMM, C = A @ B^T, 128x128 tile, BK=32, global_load_lds
// epi==1: Dout[row*ldd+col] = sqrt(max(0, sq[row] + sq[3375+col] - 2*acc))
// epi==2: Dout[row*ldd+col] = acc (fp32)
__global__ __launch_bounds__(256)
void gemm_bt(const unsigned short* __restrict__ A, const unsigned short* __restrict__ B,
             int K, int lda, int ldb, int epi,
             const float* __restrict__ sq,
             float* __restrict__ Dout, int ldd) {
  __shared__ unsigned short As[128 * BK];   // 8 KB, stride 32 (no pad)
  __shared__ unsigned short Bs[128 * BK];
  const int tid  = threadIdx.x;
  const int wave = tid >> 6, lane = tid & 63;
  const int quad = lane >> 4, l16 = lane & 15;
  const int wm = (wave >> 1) * 64, wn = (wave & 1) * 64;
  const int m0 = blockIdx.x * 128, n0 = blockIdx.y * 128;

  f32x4 acc[4][4];
#pragma unroll
  for (int i = 0; i < 4; ++i)
#pragma unroll
    for (int j = 0; j < 4; ++j) {
      f32x4 z = {0.f, 0.f, 0.f, 0.f};
      acc[i][j] = z;
    }

  const int r0  = tid >> 2;                          // 0..63
  const int qsw = (tid & 3) ^ ((tid >> 3) & 3);      // swizzled global chunk
  const int kp0 = qsw * 8;
  // LDS read slot for logical chunk `quad` of row base16+l16 (bank-conflict-free)
  const int rsw = (quad ^ ((l16 >> 1) & 3)) * 8;
  // LDS dest for global_load_lds: wave-uniform base; lanes land at +lane*16
  unsigned short* lA0 = &As[wave * 512];
  unsigned short* lA1 = &As[2048 + wave * 512];
  unsigned short* lB0 = &Bs[wave * 512];
  unsigned short* lB1 = &Bs[2048 + wave * 512];
  const unsigned short* pa0 = A + (size_t)(m0 + r0) * lda + kp0;
  const unsigned short* pa1 = A + (size_t)(m0 + r0 + 64) * lda + kp0;
  const unsigned short* pb0 = B + (size_t)(n0 + r0) * ldb + kp0;
  const unsigned short* pb1 = B + (size_t)(n0 + r0 + 64) * ldb + kp0;

  for (int k0 = 0; k0 < K; k0 += BK) {
    gl_lds16(pa0, lA0);
    gl_lds16(pa1, lA1);
    gl_lds16(pb0, lB0);
    gl_lds16(pb1, lB1);
    pa0 += BK; pa1 += BK; pb0 += BK; pb1 += BK;
    __syncthreads();   // drains vmcnt -> LDS tiles complete
    bf16x8 af[4], bfr[4];
#pragma unroll
    for (int t = 0; t < 4; ++t)
      af[t] = *reinterpret_cast<const bf16x8*>(&As[(wm + t * 16 + l16) * BK + rsw]);
#pragma unroll
    for (int t = 0; t < 4; ++t)
      bfr[t] = *reinterpret_cast<const bf16x8*>(&Bs[(wn + t * 16 + l16) * BK + rsw]);
#pragma unroll
    for (int i = 0; i < 4; ++i)
#pragma unroll
      for (int j = 0; j < 4; ++j)
        acc[i][j] = __builtin_amdgcn_mfma_f32_16x16x32_bf16(af[i], bfr[j], acc[i][j], 0, 0, 0);
    __syncthreads();
  }

  // epilogue: C/D layout col=lane&15, row=quad*4+reg
  if (epi == 2) {
#pragma unroll
    for (int i = 0; i < 4; ++i)
#pragma unroll
      for (int j = 0; j < 4; ++j) {
        int col = n0 + wn + j * 16 + l16;
        int rbase = m0 + wm + i * 16 + quad * 4;
        f32x4 v = acc[i][j];
#pragma unroll
        for (int r = 0; r < 4; ++r)
          Dout[(size_t)(rbase + r) * ldd + col] = v[r];
      }
  } else {
#pragma unroll
    for (int i = 0; i < 4; ++i)
#pragma unroll
      for (int j = 0; j < 4; ++j) {
        int col = n0 + wn + j * 16 + l16;
        int rbase = m0 + wm + i * 16 + quad * 4;
        float sc = sq[NQT + col];
        f32x4 v = acc[i][j];
#pragma unroll
        for (int r = 0; r < 4; ++r) {
          float x = sq[rbase + r] + sc - 2.f * v[r];
          Dout[(size_t)(rbase + r) * ldd + col] = sqrtf(fmaxf(x, 0.f));
        }
      }
  }
}

// ---- 2: E rows from Y (gather-add-relu-bf16) + row norms -------------------
__global__ void build_e(const float* __restrict__ Y, const float* __restrict__ bias,
                        unsigned short* __restrict__ E, float* __restrict__ sq) {
  int r = blockIdx.x, tid = threadIdx.x;
  if (r >= MROWS) {                    // pad rows: zeros
    uint4 z = {0, 0, 0, 0};
    reinterpret_cast<uint4*>(E + (size_t)r * 2048)[tid] = z;
    if (tid == 0) sq[r] = 0.f;
    return;
  }
  int x0, x1;
  if (r < NQT) {
    int n = r / 45, t = r - n * 45;
    x0 = n * 10 + P0[t]; x1 = n * 10 + P1[t];
  } else {
    int rr = r - NQT;
    int c = rr / 225, j = rr - c * 225;
    int sh = j / 45, t = j - sh * 45;
    int s = 750 + (c * 5 + sh) * 10;
    x0 = s + P0[t]; x1 = s + P1[t];
  }
  const float4* y0 = reinterpret_cast<const float4*>(Y + (size_t)x0 * 4096) + tid * 2;
  const float4* y1 = reinterpret_cast<const float4*>(Y + (size_t)x1 * 4096 + 2048) + tid * 2;
  const float4* bz = reinterpret_cast<const float4*>(bias) + tid * 2;
  float s = 0.f;
  unsigned short o[8];
#pragma unroll
  for (int h = 0; h < 2; ++h) {
    float4 a = y0[h], b = y1[h], c = bz[h];
    float v[4] = {a.x + b.x + c.x, a.y + b.y + c.y, a.z + b.z + c.z, a.w + b.w + c.w};
#pragma unroll
    for (int u = 0; u < 4; ++u) {
      float x = fmaxf(v[u], 0.f);
      unsigned short ob = f2b(x);
      o[h * 4 + u] = ob;
      float xr = b2f(ob);
      s += xr * xr;                    // norm from rounded value (matches prior)
    }
  }
  reinterpret_cast<uint4*>(E + (size_t)r * 2048)[tid] = *reinterpret_cast<uint4*>(o);
  __shared__ float red[256];
  red[tid] = s;
  __syncthreads();
  for (int st = 128; st > 0; st >>= 1) {
    if (tid < st) red[tid] += red[tid + st];
    __syncthreads();
  }
  if (tid == 0) sq[r] = red[0];
}

// ---- 4: per (c,i) stats ----------------------------------------------------
__global__ void stats_kernel(const float* __restrict__ D, float* __restrict__ ave,
                             int* __restrict__ pos, float* __restrict__ rmax) {
  int gid = blockIdx.x * 256 + threadIdx.x;
  if (gid >= 5 * NQT) return;
  int c = gid / NQT, i = gid - c * NQT;
  const float* p = D + (size_t)i * LDD + c * 225;
  float best = -1e30f; int bi = 0;
  float gm[5] = {-1e30f, -1e30f, -1e30f, -1e30f, -1e30f};
  for (int tr = 0; tr < 45; ++tr) {
#pragma unroll
    for (int sr = 0; sr < 5; ++sr) {
      int j = tr * 5 + sr;
      float v = p[j];
      if (v > best) { best = v; bi = j; }     // first-occurrence argmax
      gm[sr] = fmaxf(gm[sr], v);
    }
  }
  ave[gid]  = (gm[0] + gm[1] + gm[2] + gm[3] + gm[4]) * 0.2f;
  pos[gid]  = bi;
  rmax[gid] = best;
}

// ---- 5: dist_max -----------------------------------------------------------
__global__ void dmax_kernel(const float* __restrict__ rmax, float* __restrict__ out,
                            float* __restrict__ dmaxbuf) {
  int gid = blockIdx.x * 256 + threadIdx.x;
  if (gid >= 375) return;
  int q = gid / 5, c = gid - q * 5;
  float s = 0.f;
  for (int t = 0; t < 45; ++t) s += rmax[c * NQT + q * 45 + t];
  float v = s / 45.f;
  out[q * 5 + c] = v;
  dmaxbuf[q * 5 + c] = v;
}

// ---- 6a: record counts, parallel over query chunks -------------------------
__global__ void record_part(const float* __restrict__ D, const float* __restrict__ ave,
                            const int* __restrict__ pos, float* __restrict__ record) {
  int b = blockIdx.x;
  int c = b / 27, chunk = b - c * 27;
  int i0 = chunk * 125;
  int tid = threadIdx.x;
  __shared__ int   sp[125];
  __shared__ float sa[125];
  if (tid < 125) {
    sp[tid] = pos[c * NQT + i0 + tid];
    sa[tid] = ave[c * NQT + i0 + tid];
  }
  __syncthreads();
  float cnt[4] = {0.f, 0.f, 0.f, 0.f};
  int gcol[4];
#pragma unroll
  for (int j = 0; j < 4; ++j) {
    int col = tid + j * 256;
    gcol[j] = (col < 900) ? (col < c * 225 ? col : col + 225) : 0;
  }
  const bool act3 = (tid + 768) < 900;
  const float* Dsup = D + (size_t)(NQT + c * 225) * LDD;
  for (int ii = 0; ii < 125; ++ii) {
    const float* row = Dsup + (size_t)sp[ii] * LDD;
    float a = sa[ii];
    cnt[0] += (row[gcol[0]] > a) ? 1.f : 0.f;
    cnt[1] += (row[gcol[1]] > a) ? 1.f : 0.f;
    cnt[2] += (row[gcol[2]] > a) ? 1.f : 0.f;
    if (act3) cnt[3] += (row[gcol[3]] > a) ? 1.f : 0.f;
  }
#pragma unroll
  for (int j = 0; j < 4; ++j) {
    int col = tid + j * 256;
    if (col < 900) atomicAdd(&record[c * 900 + col], cnt[j]);
  }
}

// ---- 6b: thr + mask --------------------------------------------------------
__global__ void record_finish(const float* __restrict__ record, float* __restrict__ mask) {
  int b = blockIdx.x;                 // 0..19
  int c = b / 4, mi = b - c * 4;
  int tid = threadIdx.x;
  float r = (tid < 225) ? record[c * 900 + mi * 225 + tid] : 0.f;
  __shared__ float s1[256], s2[256];
  __shared__ float thr_s;
  s1[tid] = r;
  s2[tid] = (tid < 225 && r != 0.f) ? 1.f : 0.f;
  __syncthreads();
  for (int st = 128; st > 0; st >>= 1) {
    if (tid < st) { s1[tid] += s1[tid + st]; s2[tid] += s2[tid + st]; }
    __syncthreads();
  }
  if (tid == 0) {
    float nz = s2[0] < 1.f ? 1.f : s2[0];
    thr_s = s1[0] / nz;
  }
  __syncthreads();
  if (tid < 225) mask[(c * 4 + mi) * 225 + tid] = (r < thr_s) ? 1.f : 0.f;
}

// ---- 7: masked-mean contrast + logits --------------------------------------
__global__ void contrast_kernel(const float* __restrict__ D, const float* __restrict__ mask,
                                const float* __restrict__ dmaxbuf, float* __restrict__ out) {
  int b = blockIdx.x;                 // 0..374
  int q = b / 5, c = b - q * 5;
  int tid = threadIdx.x;
  __shared__ float red[256];
  float ms = 0.f;
  for (int e = tid; e < 900; e += 256) ms += mask[c * 900 + e];
  red[tid] = ms;
  __syncthreads();
  for (int st = 128; st > 0; st >>= 1) {
    if (tid < st) red[tid] += red[tid + st];
    __syncthreads();
  }
  float msum = red[0];
  if (msum < 1.f) msum = 1.f;
  __syncthreads();
  float acc = 0.f;
  for (int e = tid; e < 45 * 900; e += 256) {
    int t = e / 900, rest = e - t * 900;
    int mi = rest / 225, s2 = rest - mi * 225;
    int mm = mi + (mi >= c ? 1 : 0);
    float m = mask[c * 900 + rest];
    if (m != 0.f)
      acc += D[(size_t)(q * 45 + t) * LDD + mm * 225 + s2];
  }
  red[tid] = acc;
  __syncthreads();
  for (int st = 128; st > 0; st >>= 1) {
    if (tid < st) red[tid] += red[tid + st];
    __syncthreads();
  }
  if (tid == 0) {
    float contrast = red[0] / (msum * 180.f);   // /msum /45 /(WAY-1)
    float dm = dmaxbuf[q * 5 + c];
    out[375 + q * 5 + c] = dm / (contrast + dm);
  }
}

// ---------------------------------------------------------------------------
extern "C" void kernel_launch(void* const* d_in, const int* in_sizes, int n_in,
                              void* d_out, int out_size, void* d_ws, size_t ws_size,
                              hipStream_t stream) {
  const float* support = (const float*)d_in[0];
  // d_in[1] = support_labels (arange//SHOT) -- class gather is a reshape, unused
  const float* queries = (const float*)d_in[2];
  const float* W       = (const float*)d_in[3];
  const float* bias    = (const float*)d_in[4];
  float* out = (float*)d_out;

  char* ws = (char*)d_ws;
  size_t off = 0;
  unsigned short* Ws = (unsigned short*)(ws + off); off += (size_t)4096 * 2048 * 2;  // 16.8 MB
  unsigned short* Xb = (unsigned short*)(ws + off); off += (size_t)1024 * 2048 * 2;  // 4.2 MB
  float*          Y  = (float*)(ws + off);                                           // 16.8 MB (aliased)
  float*          Dm = (float*)(ws + off);          off += (size_t)MPAD * LDD * 4;   // 21.2 MB union
  unsigned short* Eb = (unsigned short*)(ws + off); off += (size_t)MPAD * 2048 * 2;  // 18.9 MB
  float* sq      = (float*)(ws + off); off += 4608 * 4 + 256;
  float* ave     = (float*)(ws + off); off += 5 * NQT * 4 + 256;
  int*   pos     = (int*)(ws + off);   off += 5 * NQT * 4 + 256;
  float* rmax    = (float*)(ws + off); off += 5 * NQT * 4 + 256;
  float* mask    = (float*)(ws + off); off += 5 * 4 * 225 * 4 + 256;
  float* dmaxbuf = (float*)(ws + off); off += 375 * 4 + 256;
  float* record  = (float*)(ws + off); off += 5 * 900 * 4 + 256;

  conv_w2<<<(2048 * 4096 / 4) / 256, 256, 0, stream>>>(W, Ws);
  conv_x<<<(1024 * 2048 / 4) / 256, 256, 0, stream>>>(queries, support, Xb);
  zero_buf<<<(5 * 900 + 255) / 256, 256, 0, stream>>>(record, 5 * 900);

  dim3 g1(1024 / 128, 4096 / 128);   // 8 x 32 = 256 blocks
  gemm_bt<<<g1, 256, 0, stream>>>(Xb, Ws, 2048, 2048, 2048, 2,
                                  nullptr, Y, 4096);

  build_e<<<MPAD, 256, 0, stream>>>(Y, bias, Eb, sq);

  dim3 g2(MPAD / 128, LDD / 128);    // 36 x 9 = 324 blocks
  gemm_bt<<<g2, 256, 0, stream>>>(Eb, Eb + (size_t)NQT * 2048, K2, K2, K2, 1,
                                  sq, Dm, LDD);

  stats_kernel<<<(5 * NQT + 255) / 256, 256, 0, stream>>>(Dm, ave, pos, rmax);
  dmax_kernel<<<2, 256, 0, stream>>>(rmax, out, dmaxbuf);
  record_part<<<135, 256, 0, stream>>>(Dm, ave, pos, record);
  record_finish<<<20, 256, 0, stream>>>(record, mask);
  contrast_kernel<<<375, 256, 0, stream>>>(Dm, mask, dmaxbuf, out);
}

// Round 5
// 287.798 us; speedup vs baseline: 2.5168x; 1.2523x over previous
//
#include <hip/hip_runtime.h>

// ---------------------------------------------------------------------------
// DistanceLoss pipeline on MI355X (gfx950)
//
// R4: tuple-gather factored out of embed GEMM (Y = X@Wsplit^T, 16.8 GFLOP).
// R5: contrast restructured: per-class msum once; one wave per (class,row)
//     masked dot product (16875 waves); tiny finish kernel.
//
//  0a. conv_w2: W fp32 -> split bf16 [4096x2048]
//  0b. conv_x : queries||supports fp32 -> bf16 X [1024x2048]
//  1. gemm_bt epi=2: Y = X @ Wsplit^T, fp32 [1024x4096]
//  2. build_e: E rows (bf16) + row norms sq
//  3. gemm_bt epi=1: D[i][j] = dist(E[i],E[3375+j]) [4608x1152]
//  4. stats / dmax / record_part / record_finish
//  5. msum_kernel / contrast_rows / contrast_finish
//
// GEMM: 128x128 tile, BK=32, global_load_lds(16B) staging, chunk-XOR swizzle
// (LDS slot (row,s) holds global chunk s^((row>>1)&3)) -> 2-way reads (free).
// ---------------------------------------------------------------------------

typedef __bf16 bf16x8 __attribute__((ext_vector_type(8)));
typedef float f32x4 __attribute__((ext_vector_type(4)));

#define NQT   3375      // 75*45 query-tuple rows
#define MROWS 4500      // 3375 query rows + 1125 support rows
#define MPAD  4608      // 36 * 128
#define K2    2048
#define LDD   1152      // padded 1125 -> 9*128
#define BK    32        // K-tile; LDS stride = 32 (UNPADDED: required by global_load_lds)

__constant__ int P0[45] = {0,0,0,0,0,0,0,0,0,
                           1,1,1,1,1,1,1,1,
                           2,2,2,2,2,2,2,
                           3,3,3,3,3,3,
                           4,4,4,4,4,
                           5,5,5,5,
                           6,6,6,
                           7,7,
                           8};
__constant__ int P1[45] = {1,2,3,4,5,6,7,8,9,
                           2,3,4,5,6,7,8,9,
                           3,4,5,6,7,8,9,
                           4,5,6,7,8,9,
                           5,6,7,8,9,
                           6,7,8,9,
                           7,8,9,
                           8,9,
                           9};

__device__ inline unsigned short f2b(float x) {
  __bf16 b = (__bf16)x;               // RNE
  return __builtin_bit_cast(unsigned short, b);
}
__device__ inline float b2f(unsigned int u16) {
  return __uint_as_float(u16 << 16);
}

// async global->LDS, 16B per lane; lds dest must be wave-uniform base + lane*16
__device__ __forceinline__ void gl_lds16(const unsigned short* g, unsigned short* l) {
  __builtin_amdgcn_global_load_lds(
      (__attribute__((address_space(1))) void*)(g),
      (__attribute__((address_space(3))) void*)(l),
      16, 0, 0);
}

// ---- 0a: W fp32 -> split bf16 [4096 x 2048] --------------------------------
__global__ void conv_w2(const float* __restrict__ W, unsigned short* __restrict__ Ws) {
  int i = blockIdx.x * 256 + threadIdx.x;           // one float4 per thread
  if (i >= (2048 * 4096) / 4) return;
  int i4 = i << 2;
  int o  = i4 >> 12;            // row in W (4096 per row)
  int k  = i4 & 4095;
  int hf = k >> 11;             // which half of K
  int kk = k & 2047;
  float4 v = reinterpret_cast<const float4*>(W)[i];
  ushort4 u;
  u.x = f2b(v.x); u.y = f2b(v.y); u.z = f2b(v.z); u.w = f2b(v.w);
  *reinterpret_cast<ushort4*>(Ws + (size_t)(o + hf * 2048) * 2048 + kk) = u;
}

// ---- 0b: X = bf16(queries || supports), rows 1000..1023 zero ---------------
__global__ void conv_x(const float* __restrict__ Q, const float* __restrict__ S,
                       unsigned short* __restrict__ X) {
  int i = blockIdx.x * 256 + threadIdx.x;           // one float4 slot
  if (i >= (1024 * 2048) / 4) return;
  ushort4 u = {0, 0, 0, 0};
  if (i < 384000) {                                  // 750*2048/4
    float4 v = reinterpret_cast<const float4*>(Q)[i];
    u.x = f2b(v.x); u.y = f2b(v.y); u.z = f2b(v.z); u.w = f2b(v.w);
  } else if (i < 512000) {                           // + 250*2048/4
    float4 v = reinterpret_cast<const float4*>(S)[i - 384000];
    u.x = f2b(v.x); u.y = f2b(v.y); u.z = f2b(v.z); u.w = f2b(v.w);
  }
  reinterpret_cast<ushort4*>(X)[i] = u;
}

__global__ void zero_buf(float* __restrict__ p, int n) {
  int i = blockIdx.x * 256 + threadIdx.x;
  if (i < n) p[i] = 0.f;
}

// ---- 1/3: bf16 MFMA GEMM, C = A @ B^T, 128x128 tile, BK=32, global_load_lds
// epi==1: Dout[row*ldd+col] = sqrt(max(0, sq[row] + sq[3375+col] - 2*acc))
// epi==2: Dout[row*ldd+col] = acc (fp32)
__global__ __launch_bounds__(256)
void gemm_bt(const unsigned short* __restrict__ A, const unsigned short* __restrict__ B,
             int K, int lda, int ldb, int epi,
             const float* __restrict__ sq,
             float* __restrict__ Dout, int ldd) {
  __shared__ unsigned short As[128 * BK];   // 8 KB, stride 32 (no pad)
  __shared__ unsigned short Bs[128 * BK];
  const int tid  = threadIdx.x;
  const int wave = tid >> 6, lane = tid & 63;
  const int quad = lane >> 4, l16 = lane & 15;
  const int wm = (wave >> 1) * 64, wn = (wave & 1) * 64;
  const int m0 = blockIdx.x * 128, n0 = blockIdx.y * 128;

  f32x4 acc[4][4];
#pragma unroll
  for (int i = 0; i < 4; ++i)
#pragma unroll
    for (int j = 0; j < 4; ++j) {
      f32x4 z = {0.f, 0.f, 0.f, 0.f};
      acc[i][j] = z;
    }

  const int r0  = tid >> 2;                          // 0..63
  const int qsw = (tid & 3) ^ ((tid >> 3) & 3);      // swizzled global chunk
  const int kp0 = qsw * 8;
  // LDS read slot for logical chunk `quad` of row base16+l16 (bank-conflict-free)
  const int rsw = (quad ^ ((l16 >> 1) & 3)) * 8;
  // LDS dest for global_load_lds: wave-uniform base; lanes land at +lane*16
  unsigned short* lA0 = &As[wave * 512];
  unsigned short* lA1 = &As[2048 + wave * 512];
  unsigned short* lB0 = &Bs[wave * 512];
  unsigned short* lB1 = &Bs[2048 + wave * 512];
  const unsigned short* pa0 = A + (size_t)(m0 + r0) * lda + kp0;
  const unsigned short* pa1 = A + (size_t)(m0 + r0 + 64) * lda + kp0;
  const unsigned short* pb0 = B + (size_t)(n0 + r0) * ldb + kp0;
  const unsigned short* pb1 = B + (size_t)(n0 + r0 + 64) * ldb + kp0;

  for (int k0 = 0; k0 < K; k0 += BK) {
    gl_lds16(pa0, lA0);
    gl_lds16(pa1, lA1);
    gl_lds16(pb0, lB0);
    gl_lds16(pb1, lB1);
    pa0 += BK; pa1 += BK; pb0 += BK; pb1 += BK;
    __syncthreads();   // drains vmcnt -> LDS tiles complete
    bf16x8 af[4], bfr[4];
#pragma unroll
    for (int t = 0; t < 4; ++t)
      af[t] = *reinterpret_cast<const bf16x8*>(&As[(wm + t * 16 + l16) * BK + rsw]);
#pragma unroll
    for (int t = 0; t < 4; ++t)
      bfr[t] = *reinterpret_cast<const bf16x8*>(&Bs[(wn + t * 16 + l16) * BK + rsw]);
#pragma unroll
    for (int i = 0; i < 4; ++i)
#pragma unroll
      for (int j = 0; j < 4; ++j)
        acc[i][j] = __builtin_amdgcn_mfma_f32_16x16x32_bf16(af[i], bfr[j], acc[i][j], 0, 0, 0);
    __syncthreads();
  }

  // epilogue: C/D layout col=lane&15, row=quad*4+reg
  if (epi == 2) {
#pragma unroll
    for (int i = 0; i < 4; ++i)
#pragma unroll
      for (int j = 0; j < 4; ++j) {
        int col = n0 + wn + j * 16 + l16;
        int rbase = m0 + wm + i * 16 + quad * 4;
        f32x4 v = acc[i][j];
#pragma unroll
        for (int r = 0; r < 4; ++r)
          Dout[(size_t)(rbase + r) * ldd + col] = v[r];
      }
  } else {
#pragma unroll
    for (int i = 0; i < 4; ++i)
#pragma unroll
      for (int j = 0; j < 4; ++j) {
        int col = n0 + wn + j * 16 + l16;
        int rbase = m0 + wm + i * 16 + quad * 4;
        float sc = sq[NQT + col];
        f32x4 v = acc[i][j];
#pragma unroll
        for (int r = 0; r < 4; ++r) {
          float x = sq[rbase + r] + sc - 2.f * v[r];
          Dout[(size_t)(rbase + r) * ldd + col] = sqrtf(fmaxf(x, 0.f));
        }
      }
  }
}

// ---- 2: E rows from Y (gather-add-relu-bf16) + row norms -------------------
__global__ void build_e(const float* __restrict__ Y, const float* __restrict__ bias,
                        unsigned short* __restrict__ E, float* __restrict__ sq) {
  int r = blockIdx.x, tid = threadIdx.x;
  if (r >= MROWS) {                    // pad rows: zeros
    uint4 z = {0, 0, 0, 0};
    reinterpret_cast<uint4*>(E + (size_t)r * 2048)[tid] = z;
    if (tid == 0) sq[r] = 0.f;
    return;
  }
  int x0, x1;
  if (r < NQT) {
    int n = r / 45, t = r - n * 45;
    x0 = n * 10 + P0[t]; x1 = n * 10 + P1[t];
  } else {
    int rr = r - NQT;
    int c = rr / 225, j = rr - c * 225;
    int sh = j / 45, t = j - sh * 45;
    int s = 750 + (c * 5 + sh) * 10;
    x0 = s + P0[t]; x1 = s + P1[t];
  }
  const float4* y0 = reinterpret_cast<const float4*>(Y + (size_t)x0 * 4096) + tid * 2;
  const float4* y1 = reinterpret_cast<const float4*>(Y + (size_t)x1 * 4096 + 2048) + tid * 2;
  const float4* bz = reinterpret_cast<const float4*>(bias) + tid * 2;
  float s = 0.f;
  unsigned short o[8];
#pragma unroll
  for (int h = 0; h < 2; ++h) {
    float4 a = y0[h], b = y1[h], c = bz[h];
    float v[4] = {a.x + b.x + c.x, a.y + b.y + c.y, a.z + b.z + c.z, a.w + b.w + c.w};
#pragma unroll
    for (int u = 0; u < 4; ++u) {
      float x = fmaxf(v[u], 0.f);
      unsigned short ob = f2b(x);
      o[h * 4 + u] = ob;
      float xr = b2f(ob);
      s += xr * xr;                    // norm from rounded value
    }
  }
  reinterpret_cast<uint4*>(E + (size_t)r * 2048)[tid] = *reinterpret_cast<uint4*>(o);
  __shared__ float red[256];
  red[tid] = s;
  __syncthreads();
  for (int st = 128; st > 0; st >>= 1) {
    if (tid < st) red[tid] += red[tid + st];
    __syncthreads();
  }
  if (tid == 0) sq[r] = red[0];
}

// ---- 4: per (c,i) stats ----------------------------------------------------
__global__ void stats_kernel(const float* __restrict__ D, float* __restrict__ ave,
                             int* __restrict__ pos, float* __restrict__ rmax) {
  int gid = blockIdx.x * 256 + threadIdx.x;
  if (gid >= 5 * NQT) return;
  int c = gid / NQT, i = gid - c * NQT;
  const float* p = D + (size_t)i * LDD + c * 225;
  float best = -1e30f; int bi = 0;
  float gm[5] = {-1e30f, -1e30f, -1e30f, -1e30f, -1e30f};
  for (int tr = 0; tr < 45; ++tr) {
#pragma unroll
    for (int sr = 0; sr < 5; ++sr) {
      int j = tr * 5 + sr;
      float v = p[j];
      if (v > best) { best = v; bi = j; }     // first-occurrence argmax
      gm[sr] = fmaxf(gm[sr], v);
    }
  }
  ave[gid]  = (gm[0] + gm[1] + gm[2] + gm[3] + gm[4]) * 0.2f;
  pos[gid]  = bi;
  rmax[gid] = best;
}

// ---- 5: dist_max -----------------------------------------------------------
__global__ void dmax_kernel(const float* __restrict__ rmax, float* __restrict__ out,
                            float* __restrict__ dmaxbuf) {
  int gid = blockIdx.x * 256 + threadIdx.x;
  if (gid >= 375) return;
  int q = gid / 5, c = gid - q * 5;
  float s = 0.f;
  for (int t = 0; t < 45; ++t) s += rmax[c * NQT + q * 45 + t];
  float v = s / 45.f;
  out[q * 5 + c] = v;
  dmaxbuf[q * 5 + c] = v;
}

// ---- 6a: record counts, parallel over query chunks -------------------------
__global__ void record_part(const float* __restrict__ D, const float* __restrict__ ave,
                            const int* __restrict__ pos, float* __restrict__ record) {
  int b = blockIdx.x;
  int c = b / 27, chunk = b - c * 27;
  int i0 = chunk * 125;
  int tid = threadIdx.x;
  __shared__ int   sp[125];
  __shared__ float sa[125];
  if (tid < 125) {
    sp[tid] = pos[c * NQT + i0 + tid];
    sa[tid] = ave[c * NQT + i0 + tid];
  }
  __syncthreads();
  float cnt[4] = {0.f, 0.f, 0.f, 0.f};
  int gcol[4];
#pragma unroll
  for (int j = 0; j < 4; ++j) {
    int col = tid + j * 256;
    gcol[j] = (col < 900) ? (col < c * 225 ? col : col + 225) : 0;
  }
  const bool act3 = (tid + 768) < 900;
  const float* Dsup = D + (size_t)(NQT + c * 225) * LDD;
  for (int ii = 0; ii < 125; ++ii) {
    const float* row = Dsup + (size_t)sp[ii] * LDD;
    float a = sa[ii];
    cnt[0] += (row[gcol[0]] > a) ? 1.f : 0.f;
    cnt[1] += (row[gcol[1]] > a) ? 1.f : 0.f;
    cnt[2] += (row[gcol[2]] > a) ? 1.f : 0.f;
    if (act3) cnt[3] += (row[gcol[3]] > a) ? 1.f : 0.f;
  }
#pragma unroll
  for (int j = 0; j < 4; ++j) {
    int col = tid + j * 256;
    if (col < 900) atomicAdd(&record[c * 900 + col], cnt[j]);
  }
}

// ---- 6b: thr + mask --------------------------------------------------------
__global__ void record_finish(const float* __restrict__ record, float* __restrict__ mask) {
  int b = blockIdx.x;                 // 0..19
  int c = b / 4, mi = b - c * 4;
  int tid = threadIdx.x;
  float r = (tid < 225) ? record[c * 900 + mi * 225 + tid] : 0.f;
  __shared__ float s1[256], s2[256];
  __shared__ float thr_s;
  s1[tid] = r;
  s2[tid] = (tid < 225 && r != 0.f) ? 1.f : 0.f;
  __syncthreads();
  for (int st = 128; st > 0; st >>= 1) {
    if (tid < st) { s1[tid] += s1[tid + st]; s2[tid] += s2[tid + st]; }
    __syncthreads();
  }
  if (tid == 0) {
    float nz = s2[0] < 1.f ? 1.f : s2[0];
    thr_s = s1[0] / nz;
  }
  __syncthreads();
  if (tid < 225) mask[(c * 4 + mi) * 225 + tid] = (r < thr_s) ? 1.f : 0.f;
}

// ---- 7a: per-class mask sums ----------------------------------------------
__global__ void msum_kernel(const float* __restrict__ mask, float* __restrict__ msum) {
  int c = blockIdx.x, tid = threadIdx.x;
  float s = 0.f;
  for (int e = tid; e < 900; e += 256) s += mask[c * 900 + e];
  __shared__ float red[256];
  red[tid] = s;
  __syncthreads();
  for (int st = 128; st > 0; st >>= 1) {
    if (tid < st) red[tid] += red[tid + st];
    __syncthreads();
  }
  if (tid == 0) msum[c] = red[0] < 1.f ? 1.f : red[0];
}

// ---- 7b: masked row dot products: S[c][i] = sum_col mask[c][col]*D[i,gcol] -
// one wave per (c, row); grid (ceil(3375/4), 5), block 256 = 4 waves
__global__ __launch_bounds__(256)
void contrast_rows(const float* __restrict__ D, const float* __restrict__ mask,
                   float* __restrict__ S) {
  int wave = threadIdx.x >> 6, lane = threadIdx.x & 63;
  int i = blockIdx.x * 4 + wave;
  int c = blockIdx.y;
  if (i >= NQT) return;
  const float* row = D + (size_t)i * LDD;
  const float* mk  = mask + c * 900;
  const int cbase = c * 225;
  float acc = 0.f;
#pragma unroll
  for (int k = 0; k < 15; ++k) {
    int col = k * 64 + lane;
    if (col < 900) {
      int gcol = col + (col >= cbase ? 225 : 0);
      acc += mk[col] * row[gcol];
    }
  }
#pragma unroll
  for (int s = 32; s > 0; s >>= 1) acc += __shfl_down(acc, s, 64);
  if (lane == 0) S[c * NQT + i] = acc;
}

// ---- 7c: finish: contrast + logits -----------------------------------------
__global__ void contrast_finish(const float* __restrict__ S, const float* __restrict__ msum,
                                const float* __restrict__ dmaxbuf, float* __restrict__ out) {
  int gid = blockIdx.x * 256 + threadIdx.x;
  if (gid >= 375) return;
  int q = gid / 5, c = gid - q * 5;
  float s = 0.f;
  for (int t = 0; t < 45; ++t) s += S[c * NQT + q * 45 + t];
  float contrast = s / (msum[c] * 180.f);       // /msum /45 /(WAY-1)
  float dm = dmaxbuf[q * 5 + c];
  out[375 + q * 5 + c] = dm / (contrast + dm);
}

// ---------------------------------------------------------------------------
extern "C" void kernel_launch(void* const* d_in, const int* in_sizes, int n_in,
                              void* d_out, int out_size, void* d_ws, size_t ws_size,
                              hipStream_t stream) {
  const float* support = (const float*)d_in[0];
  // d_in[1] = support_labels (arange//SHOT) -- class gather is a reshape, unused
  const float* queries = (const float*)d_in[2];
  const float* W       = (const float*)d_in[3];
  const float* bias    = (const float*)d_in[4];
  float* out = (float*)d_out;

  char* ws = (char*)d_ws;
  size_t off = 0;
  unsigned short* Ws = (unsigned short*)(ws + off); off += (size_t)4096 * 2048 * 2;  // 16.8 MB
  unsigned short* Xb = (unsigned short*)(ws + off); off += (size_t)1024 * 2048 * 2;  // 4.2 MB
  float*          Y  = (float*)(ws + off);                                           // 16.8 MB (aliased)
  float*          Dm = (float*)(ws + off);          off += (size_t)MPAD * LDD * 4;   // 21.2 MB union
  unsigned short* Eb = (unsigned short*)(ws + off); off += (size_t)MPAD * 2048 * 2;  // 18.9 MB
  float* sq      = (float*)(ws + off); off += 4608 * 4 + 256;
  float* ave     = (float*)(ws + off); off += 5 * NQT * 4 + 256;
  int*   pos     = (int*)(ws + off);   off += 5 * NQT * 4 + 256;
  float* rmax    = (float*)(ws + off); off += 5 * NQT * 4 + 256;
  float* mask    = (float*)(ws + off); off += 5 * 4 * 225 * 4 + 256;
  float* dmaxbuf = (float*)(ws + off); off += 375 * 4 + 256;
  float* record  = (float*)(ws + off); off += 5 * 900 * 4 + 256;
  float* Sbuf    = (float*)(ws + off); off += 5 * NQT * 4 + 256;
  float* msum    = (float*)(ws + off); off += 5 * 4 + 256;

  conv_w2<<<(2048 * 4096 / 4) / 256, 256, 0, stream>>>(W, Ws);
  conv_x<<<(1024 * 2048 / 4) / 256, 256, 0, stream>>>(queries, support, Xb);
  zero_buf<<<(5 * 900 + 255) / 256, 256, 0, stream>>>(record, 5 * 900);

  dim3 g1(1024 / 128, 4096 / 128);   // 8 x 32 = 256 blocks
  gemm_bt<<<g1, 256, 0, stream>>>(Xb, Ws, 2048, 2048, 2048, 2,
                                  nullptr, Y, 4096);

  build_e<<<MPAD, 256, 0, stream>>>(Y, bias, Eb, sq);

  dim3 g2(MPAD / 128, LDD / 128);    // 36 x 9 = 324 blocks
  gemm_bt<<<g2, 256, 0, stream>>>(Eb, Eb + (size_t)NQT * 2048, K2, K2, K2, 1,
                                  sq, Dm, LDD);

  stats_kernel<<<(5 * NQT + 255) / 256, 256, 0, stream>>>(Dm, ave, pos, rmax);
  dmax_kernel<<<2, 256, 0, stream>>>(rmax, out, dmaxbuf);
  record_part<<<135, 256, 0, stream>>>(Dm, ave, pos, record);
  record_finish<<<20, 256, 0, stream>>>(record, mask);
  msum_kernel<<<5, 256, 0, stream>>>(mask, msum);
  dim3 gc((NQT + 3) / 4, 5);         // 844 x 5 blocks, 1 wave per (c,row)
  contrast_rows<<<gc, 256, 0, stream>>>(Dm, mask, Sbuf);
  contrast_finish<<<2, 256, 0, stream>>>(Sbuf, msum, dmaxbuf, out);
}